// Round 10
// baseline (5080.211 us; speedup 1.0000x reference)
//
#include <hip/hip_runtime.h>
#include <math.h>
#include <stdint.h>

#define NSEQ 2048
#define D 512
#define V 512
#define NB 8            // column-slice blocks per pipeline stage
#define CPB 64          // D / NB
#define RING 64         // ring depth (steps)
#define RMASK (RING - 1)
#define ACK_MAGIC 0x0ACEull

// ---------------------------------------------------------------------------
// Dual-path tagged sync, NO sticky state. poll_both is the R6-measured-good
// SERIAL form (R7's always-wait-slow variant: 4335us, reverted).
//  fast ring: plain (workgroup-scope) store -> producer XCD's L2; sc0 load
//             (bypasses L1) hits the shared L2 iff consumer is on the SAME
//             XCD (~250cy). May be arbitrarily stale otherwise.
//  slow ring: relaxed agent-scope atomics -> IF-level, any placement (~700cy).
// R10 lever: FLAG-GATED WAVE-LEVEL DETECT on the two self-recurrence rings
// (ring1/stage0, ring2/stage1). Insight: wave w of every block waits on
// exactly ONE producer wave (slice w), whose 64 value stores land together;
// per-thread polling made ~3500 threads/stage hammer L2 with serialized
// sc0+agent loads (contended granularity ~1500cy, B2 takes max of 8).
// Producer: 64 value publish2 -> wave-wide s_waitcnt vmcnt(0) (stores acked)
// -> lane0 publishes per-(step,slice) flag (fast+slow). Consumer wave: all
// lanes spin on the ONE flag address (1 txn/iter, ~300cy granularity), then
// one coalesced 64-lane value read on the path the flag fired, per-value
// tag check, poll_both fallback on any mismatch -> correctness identical
// (tags authoritative; flag is only a hint). Cross-stage prefetched
// poll_slow paths and stage 3 untouched.
// ---------------------------------------------------------------------------
__device__ __forceinline__ bool tag_ok(uint64_t u, uint32_t tag) {
    return (uint32_t)(u >> 32) == tag;
}
__device__ __forceinline__ float tv_val(uint64_t u) {
    return __uint_as_float((uint32_t)u);
}
__device__ __forceinline__ uint64_t ld_fast(const uint64_t* p) {
    uint64_t u;
    asm volatile("global_load_dwordx2 %0, %1, off sc0\n\ts_waitcnt vmcnt(0)"
                 : "=v"(u) : "v"(p) : "memory");
    return u;
}
__device__ __forceinline__ uint64_t ld_slow(uint64_t* p) {
    return __hip_atomic_load(p, __ATOMIC_RELAXED, __HIP_MEMORY_SCOPE_AGENT);
}
__device__ __forceinline__ void publish2(uint64_t* fp, uint64_t* sp,
                                         float v, uint32_t tag) {
    uint64_t u = ((uint64_t)tag << 32) | (uint64_t)__float_as_uint(v);
    __hip_atomic_store(fp, u, __ATOMIC_RELAXED, __HIP_MEMORY_SCOPE_WORKGROUP);
    __hip_atomic_store(sp, u, __ATOMIC_RELAXED, __HIP_MEMORY_SCOPE_AGENT);
}
__device__ __forceinline__ void publish_slow(uint64_t* sp, float v,
                                             uint32_t tag) {
    uint64_t u = ((uint64_t)tag << 32) | (uint64_t)__float_as_uint(v);
    __hip_atomic_store(sp, u, __ATOMIC_RELAXED, __HIP_MEMORY_SCOPE_AGENT);
}
// alternate fast/slow probes; slow probe guarantees progress (R6 form)
__device__ __forceinline__ float poll_both(uint64_t* fp, uint64_t* sp,
                                           uint32_t tag) {
    while (true) {
        uint64_t u = ld_fast(fp);
        if (tag_ok(u, tag)) return tv_val(u);
        u = ld_slow(sp);
        if (tag_ok(u, tag)) return tv_val(u);
    }
}
__device__ __forceinline__ float poll_slow(uint64_t* p, uint32_t tag) {
    while (true) {
        uint64_t u = ld_slow(p);
        if (tag_ok(u, tag)) return tv_val(u);
    }
}
// flag-gated wave-level fetch from a self-recurrence ring (R10).
// All lanes spin on ONE flag address; value read on the path that fired;
// per-value tag verified; any mismatch -> poll_both fallback (bulletproof).
__device__ __forceinline__ float wave_fetch(uint64_t* ffp, uint64_t* fsp,
                                            uint64_t* vfp, uint64_t* vsp,
                                            uint32_t tag) {
    bool fastpath;
    while (true) {
        uint64_t u = ld_fast(ffp);
        if (tag_ok(u, tag)) { fastpath = true; break; }
        u = ld_slow(fsp);
        if (tag_ok(u, tag)) { fastpath = false; break; }
    }
    uint64_t uv = fastpath ? ld_fast(vfp) : ld_slow(vsp);
    if (tag_ok(uv, tag)) return tv_val(uv);
    return poll_both(vfp, vsp, tag);
}

// cross-stage consumer progress (flow control for ring reuse).
// Margin check: producer step sp < consumer_step - 16 + (RING-4) ->
// clobbered slot tag sp-64 is always older than anything still needed.
__device__ __forceinline__ void report(uint64_t* p, int s) {
    uint64_t u = (ACK_MAGIC << 48) | (uint32_t)s;
    __hip_atomic_store(p, u, __ATOMIC_RELAXED, __HIP_MEMORY_SCOPE_AGENT);
}
__device__ __forceinline__ void throttle(uint64_t* prog, int s, int& cached) {
    if (s - cached < RING - 4) return;
    while (true) {
        int mn = 0x7fffffff;
#pragma unroll
        for (int i = 0; i < NB; ++i) {
            uint64_t u = __hip_atomic_load(&prog[i], __ATOMIC_RELAXED,
                                           __HIP_MEMORY_SCOPE_AGENT);
            int v = ((u >> 48) == ACK_MAGIC) ? (int)(uint32_t)u : 0;
            mn = (v < mn) ? v : mn;
        }
        cached = mn;
        if (s - cached < RING - 4) return;
    }
}

__device__ __forceinline__ float fast_tanh(float x) {
    return 1.0f - 2.0f / (__expf(2.0f * x) + 1.0f);
}

__device__ __forceinline__ float mat_part(const float* sh, const float* wreg,
                                          int w) {
    const float4* v4 = (const float4*)&sh[w << 6];
    float a0 = 0.f, a1 = 0.f, a2 = 0.f, a3 = 0.f;
#pragma unroll
    for (int t = 0; t < 16; ++t) {
        float4 x = v4[t];
        a0 += x.x * wreg[4 * t + 0];
        a1 += x.y * wreg[4 * t + 1];
        a2 += x.z * wreg[4 * t + 2];
        a3 += x.w * wreg[4 * t + 3];
    }
    return (a0 + a1) + (a2 + a3);
}
__device__ __forceinline__ float mat_part2(const float* shx, const float* shh,
                                           const float* wx, const float* wh,
                                           int w) {
    const float4* x4 = (const float4*)&shx[w << 6];
    const float4* h4 = (const float4*)&shh[w << 6];
    float a0 = 0.f, a1 = 0.f, a2 = 0.f, a3 = 0.f;
#pragma unroll
    for (int t = 0; t < 16; ++t) {
        float4 xv = x4[t];
        float4 hv = h4[t];
        a0 += xv.x * wx[4 * t + 0] + hv.x * wh[4 * t + 0];
        a1 += xv.y * wx[4 * t + 1] + hv.y * wh[4 * t + 1];
        a2 += xv.z * wx[4 * t + 2] + hv.z * wh[4 * t + 2];
        a3 += xv.w * wx[4 * t + 3] + hv.w * wh[4 * t + 3];
    }
    return (a0 + a1) + (a2 + a3);
}

// ---------------------------------------------------------------------------
// X1 = gather(emb, nums) @ Wxh1 + b1
// ---------------------------------------------------------------------------
template <int TM>
__global__ void gemm_rows(const int* __restrict__ nums,
                          const float* __restrict__ emb,
                          const float* __restrict__ W,
                          const float* __restrict__ bias,
                          float* __restrict__ out)
{
    __shared__ float xs[TM][D];
    const int tid = threadIdx.x;               // 256
    const int r0 = blockIdx.x * TM;

    for (int m = 0; m < TM; ++m) {
        const float* xr = emb + (size_t)nums[r0 + m] * D;
        for (int idx = tid; idx < D; idx += 256) xs[m][idx] = xr[idx];
    }
    __syncthreads();

    const int j0 = tid, j1 = tid + 256;
    float acc0[TM], acc1[TM];
#pragma unroll
    for (int m = 0; m < TM; ++m) { acc0[m] = 0.f; acc1[m] = 0.f; }

    for (int k = 0; k < D; ++k) {
        const float w0 = W[(size_t)k * D + j0];
        const float w1 = W[(size_t)k * D + j1];
#pragma unroll
        for (int m = 0; m < TM; ++m) {
            const float x = xs[m][k];
            acc0[m] += x * w0;
            acc1[m] += x * w1;
        }
    }
    const float bb0 = bias[j0], bb1 = bias[j1];
#pragma unroll
    for (int m = 0; m < TM; ++m) {
        out[(size_t)(r0 + m) * D + j0] = acc0[m] + bb0;
        out[(size_t)(r0 + m) * D + j1] = acc1[m] + bb1;
    }
}

__global__ void prep_exp(const float* __restrict__ T, float* __restrict__ expT)
{
    const int i = blockIdx.x * 512 + threadIdx.x;
    expT[i] = __expf(T[i]);
}

// ---------------------------------------------------------------------------
// 4-stage pipeline. Launch 64 blocks; active: stage = blockIdx&7 in [0,4),
// slice = blockIdx>>3 (round-robin puts a stage's 8 blocks on one XCD ->
// fast ring works; slow probes keep it correct regardless).
// Publisher = the one wave owning this block's columns (R8, 3648us).
// Stages 0-2: ONE barrier per step, part[] double-buffered (R9, 3493us).
// R10: flag-gated wave-level detect on ring1/ring2 self-recurrence.
// ---------------------------------------------------------------------------
__global__ void __launch_bounds__(512, 1)
pipe_all(const float* __restrict__ X1,
         const float* __restrict__ Whh1,
         const float* __restrict__ Wxh2,
         const float* __restrict__ Whh2,
         const float* __restrict__ b2,
         const float* __restrict__ Wl,
         const float* __restrict__ bl,
         const float* __restrict__ expT,
         uint64_t* __restrict__ ring1f, uint64_t* __restrict__ ring1s,
         uint64_t* __restrict__ ring2f, uint64_t* __restrict__ ring2s,
         uint64_t* __restrict__ ringOs,
         uint64_t* __restrict__ ringFf, uint64_t* __restrict__ ringFs,
         uint64_t* __restrict__ prog1,
         uint64_t* __restrict__ prog2,
         uint64_t* __restrict__ progO,
         uint64_t* __restrict__ flag1f, uint64_t* __restrict__ flag1s,
         uint64_t* __restrict__ flag2f, uint64_t* __restrict__ flag2s,
         float* __restrict__ out)
{
    __shared__ float sh1[D];
    __shared__ float sh2[D];
    __shared__ float part[2][D];
    __shared__ float own[CPB];
    __shared__ float wM[1];

    const int stage = blockIdx.x & 7;
    if (stage >= 4) return;
    const int slice = blockIdx.x >> 3;

    const int tid = threadIdx.x;      // 512
    const int w = tid >> 6, l = tid & 63;
    const int jbase = slice * CPB;
    const bool mine = (w == slice);   // publisher wave (wave-uniform)
    int cached = 0;

    if (stage == 0) {
        float wreg[64];
#pragma unroll
        for (int t = 0; t < 64; ++t)
            wreg[t] = Whh1[(size_t)(w * 64 + t) * D + jbase + l];
        float myreg = 0.f;

        for (int s = 0; s < NSEQ; ++s) {
            const float xpre = mine ? X1[(size_t)s * D + tid] : 0.f;
            float hv;
            if (s == 0)    hv = 0.f;
            else if (mine) hv = myreg;
            else {
                const int slot = (s - 1) & RMASK;
                hv = wave_fetch(&flag1f[(size_t)slot * NB + w],
                                &flag1s[(size_t)slot * NB + w],
                                &ring1f[(size_t)slot * D + tid],
                                &ring1s[(size_t)slot * D + tid],
                                (uint32_t)(s - 1));
            }
            sh1[tid] = hv;                      // wave-local: only wave w
            part[s & 1][tid] = mat_part(sh1, wreg, w);   // reads sh1[w*64..]
            __syncthreads();                    // B2: part[s&1] ready
            if (mine) {
                const int c = tid & 63;
                float sum = 0.f;
#pragma unroll
                for (int ww = 0; ww < 8; ++ww) sum += part[s & 1][(ww << 6) + c];
                const float g = fast_tanh(sum + xpre);
                myreg = g;
                throttle(prog1, s, cached);
                publish2(&ring1f[(size_t)(s & RMASK) * D + tid],
                         &ring1s[(size_t)(s & RMASK) * D + tid],
                         g, (uint32_t)s);
                asm volatile("s_waitcnt vmcnt(0)" ::: "memory");
                if (l == 0)   // values acked -> raise flag (fast+slow)
                    publish2(&flag1f[(size_t)(s & RMASK) * NB + slice],
                             &flag1s[(size_t)(s & RMASK) * NB + slice],
                             0.f, (uint32_t)s);
            }
        }
    } else if (stage == 1) {
        float wx[64], wh[64];
#pragma unroll
        for (int t = 0; t < 64; ++t) {
            wx[t] = Wxh2[(size_t)(w * 64 + t) * D + jbase + l];
            wh[t] = Whh2[(size_t)(w * 64 + t) * D + jbase + l];
        }
        const float bpre = mine ? b2[tid] : 0.f;
        float myreg = 0.f;
        uint64_t pre = 0;   // prefetched ring1 slow value for step s

        for (int s = 0; s < NSEQ; ++s) {
            float h1v;
            if (tag_ok(pre, (uint32_t)s)) h1v = tv_val(pre);
            else h1v = poll_slow(&ring1s[(size_t)(s & RMASK) * D + tid],
                                 (uint32_t)s);
            float h2v;
            if (s == 0)    h2v = 0.f;
            else if (mine) h2v = myreg;
            else {
                const int slot = (s - 1) & RMASK;
                h2v = wave_fetch(&flag2f[(size_t)slot * NB + w],
                                 &flag2s[(size_t)slot * NB + w],
                                 &ring2f[(size_t)slot * D + tid],
                                 &ring2s[(size_t)slot * D + tid],
                                 (uint32_t)(s - 1));
            }
            sh1[tid] = h1v;
            sh2[tid] = h2v;
            if (s + 1 < NSEQ)   // prefetch next h1; hides under matvec
                pre = ld_slow(&ring1s[(size_t)((s + 1) & RMASK) * D + tid]);
            part[s & 1][tid] = mat_part2(sh1, sh2, wx, wh, w);
            __syncthreads();                    // B2
            if (mine) {
                const int c = tid & 63;
                float sum = 0.f;
#pragma unroll
                for (int ww = 0; ww < 8; ++ww) sum += part[s & 1][(ww << 6) + c];
                const float g = fast_tanh(sum + bpre);
                myreg = g;
                throttle(prog2, s, cached);
                publish2(&ring2f[(size_t)(s & RMASK) * D + tid],
                         &ring2s[(size_t)(s & RMASK) * D + tid],
                         g, (uint32_t)s);
                asm volatile("s_waitcnt vmcnt(0)" ::: "memory");
                if (l == 0)
                    publish2(&flag2f[(size_t)(s & RMASK) * NB + slice],
                             &flag2s[(size_t)(s & RMASK) * NB + slice],
                             0.f, (uint32_t)s);
            }
            if (tid == 0 && (s & 15) == 15) report(&prog1[slice], s);
        }
    } else if (stage == 2) {
        float wreg[64];
#pragma unroll
        for (int t = 0; t < 64; ++t)
            wreg[t] = Wl[(size_t)(w * 64 + t) * V + jbase + l];
        const float bpre = mine ? bl[tid] : 0.f;
        uint64_t pre = 0;

        for (int s = 0; s < NSEQ; ++s) {
            float hv;
            if (tag_ok(pre, (uint32_t)s)) hv = tv_val(pre);
            else hv = poll_slow(&ring2s[(size_t)(s & RMASK) * D + tid],
                                (uint32_t)s);
            sh1[tid] = hv;
            if (s + 1 < NSEQ)
                pre = ld_slow(&ring2s[(size_t)((s + 1) & RMASK) * D + tid]);
            part[s & 1][tid] = mat_part(sh1, wreg, w);
            __syncthreads();                    // B2
            if (mine) {
                const int c = tid & 63;
                float sum = 0.f;
#pragma unroll
                for (int ww = 0; ww < 8; ++ww) sum += part[s & 1][(ww << 6) + c];
                throttle(progO, s, cached);
                publish_slow(&ringOs[(size_t)(s & RMASK) * V + tid],
                             sum + bpre, (uint32_t)s);
            }
            if (tid == 0 && (s & 15) == 15) report(&prog2[slice], s);
        }
    } else {
        // forward CRF (unchanged from R9-measured structure):
        // f_s[k] = O[s][k] + LSE_j(f_{s-1}[j] + T[j,k]); out = f_{n-1}[EOS=1]
        // Shift M = f_{s-1}[jbase] (block-uniform, via wM[0]); exact LSE
        // shift, harness-verified absmax=0.0 and perf-neutral (not gating).
        const int lcol = (w << 3) + (l & 7);
        const int gcol = jbase + lcol;
        const bool pub = (l < 8);
        const bool ownr = (tid >= jbase) && (tid < jbase + CPB);
        float wreg[64];
#pragma unroll
        for (int t = 0; t < 64; ++t)
            wreg[t] = expT[(size_t)(w * 64 + t) * V + jbase + l];

        float creg;
        if (tid == 0) { creg = poll_slow(&ringOs[0], 0u); wM[0] = creg; }
        else creg = -1e30f;
        __syncthreads();   // one-time: initial M visible
        uint64_t preO = 0;

        for (int s = 1; s < NSEQ; ++s) {
            const float M = wM[0];   // written last iter, ordered by B3
            if (s > 1) {
                if (ownr) creg = own[tid - jbase];
                else      creg = poll_both(
                              &ringFf[(size_t)((s - 1) & RMASK) * V + tid],
                              &ringFs[(size_t)((s - 1) & RMASK) * V + tid],
                              (uint32_t)(s - 1));
            }
            float opre = 0.f;
            if (pub) {
                if (tag_ok(preO, (uint32_t)s)) opre = tv_val(preO);
                else opre = poll_slow(&ringOs[(size_t)(s & RMASK) * V + gcol],
                                      (uint32_t)s);
            }

            sh1[tid] = __expf(creg - M);
            __syncthreads();                       // B1
            if (pub && s + 1 < NSEQ)
                preO = ld_slow(&ringOs[(size_t)((s + 1) & RMASK) * V + gcol]);
            part[0][tid] = mat_part(sh1, wreg, w);
            __syncthreads();                       // B2

            if (pub) {
                float sum = 0.f;
#pragma unroll
                for (int ww = 0; ww < 8; ++ww) sum += part[0][(ww << 6) + lcol];
                const float cn = opre + M + __logf(sum);
                if (s < NSEQ - 1) {
                    own[lcol] = cn;
                    if (lcol == 0) wM[0] = cn;     // next step's shift
                    publish2(&ringFf[(size_t)(s & RMASK) * V + gcol],
                             &ringFs[(size_t)(s & RMASK) * V + gcol],
                             cn, (uint32_t)s);
                } else if (gcol == 1) {
                    out[0] = cn;           // f_{n-1}[EOS=1]
                }
            }
            if (tid == 0 && (s & 15) == 15) report(&progO[slice], s);
            __syncthreads();   // B3: protects own[]/wM for next iteration
        }
    }
}

// ---------------------------------------------------------------------------
extern "C" void kernel_launch(void* const* d_in, const int* in_sizes, int n_in,
                              void* d_out, int out_size, void* d_ws, size_t ws_size,
                              hipStream_t stream)
{
    const int*   nums = (const int*)d_in[0];
    const float* emb  = (const float*)d_in[1];
    const float* Wxh1 = (const float*)d_in[2];
    const float* Whh1 = (const float*)d_in[3];
    const float* b1   = (const float*)d_in[4];
    const float* Wxh2 = (const float*)d_in[5];
    const float* Whh2 = (const float*)d_in[6];
    const float* b2   = (const float*)d_in[7];
    const float* Wl   = (const float*)d_in[8];
    const float* bl   = (const float*)d_in[9];
    const float* T    = (const float*)d_in[10];
    float* out = (float*)d_out;

    // workspace (~7 MB): X1 + expT + 7 rings + progress + 4 flag arrays
    float* Xbuf = (float*)d_ws;                         // [NSEQ*D]
    float* expT = Xbuf + (size_t)NSEQ * D;              // [V*V]
    uint64_t* ring1f = (uint64_t*)(expT + (size_t)V * V);
    uint64_t* ring1s = ring1f + (size_t)RING * D;
    uint64_t* ring2f = ring1s + (size_t)RING * D;
    uint64_t* ring2s = ring2f + (size_t)RING * D;
    uint64_t* ringOs = ring2s + (size_t)RING * D;
    uint64_t* ringFf = ringOs + (size_t)RING * V;
    uint64_t* ringFs = ringFf + (size_t)RING * V;
    uint64_t* prog1  = ringFs + (size_t)RING * V;       // [NB]
    uint64_t* prog2  = prog1 + NB;                      // [NB]
    uint64_t* progO  = prog2 + NB;                      // [NB]
    uint64_t* flag1f = progO + NB;                      // [RING*NB]
    uint64_t* flag1s = flag1f + (size_t)RING * NB;
    uint64_t* flag2f = flag1s + (size_t)RING * NB;
    uint64_t* flag2s = flag2f + (size_t)RING * NB;

    gemm_rows<8><<<NSEQ / 8, 256, 0, stream>>>(nums, emb, Wxh1, b1, Xbuf);
    prep_exp<<<V * V / 512, 512, 0, stream>>>(T, expT);
    pipe_all<<<64, 512, 0, stream>>>(Xbuf, Whh1, Wxh2, Whh2, b2, Wl, bl, expT,
                                     ring1f, ring1s, ring2f, ring2s, ringOs,
                                     ringFf, ringFs, prog1, prog2, progO,
                                     flag1f, flag1s, flag2f, flag2s, out);
}

// Round 11
// 2898.123 us; speedup vs baseline: 1.7529x; 1.7529x over previous
//
#include <hip/hip_runtime.h>
#include <math.h>
#include <stdint.h>

#define NSEQ 2048
#define D 512
#define V 512
#define NB 8            // column-slice blocks per pipeline stage
#define CPB 64          // D / NB
#define RING 64         // ring depth (steps)
#define RMASK (RING - 1)
#define ACK_MAGIC 0x0ACEull

// ---------------------------------------------------------------------------
// Dual-path tagged sync, NO sticky state. poll_both is the R6-measured-good
// SERIAL form. Detect-mechanics history (do not revisit):
//   R7  always-wait-slow "overlap":       3715 -> 4335us  (success path +500cy)
//   R10 flag-gated wave detect:           3493 -> 5515us  (serialized
//        vmcnt-drain+flag AFTER value; per-thread polling was already a
//        prefetch pipeline -> detect ~ transit only)
// Structural removals won: R8 pub-wave remap -80cy, R9 B1 removal -180cy.
//  fast ring: plain (workgroup-scope) store -> producer XCD's L2; sc0 load
//             hits the shared L2 iff consumer is on the SAME XCD (~250cy).
//  slow ring: relaxed agent-scope atomics -> IF-level, any placement (~700cy).
// R11 lever: SPLIT old stage 1. Wxh2·h1+b2 has no recurrence -> moved to a
// feed-forward stage (deeply pipelined, off the critical path). The h2
// recurrence keeps ONE matvec + ONE self-detect, same shape as stage 0.
// 5 stages x 8 slices = 40 of 64 blocks (spares were idle anyway).
// ---------------------------------------------------------------------------
__device__ __forceinline__ bool tag_ok(uint64_t u, uint32_t tag) {
    return (uint32_t)(u >> 32) == tag;
}
__device__ __forceinline__ float tv_val(uint64_t u) {
    return __uint_as_float((uint32_t)u);
}
__device__ __forceinline__ uint64_t ld_fast(const uint64_t* p) {
    uint64_t u;
    asm volatile("global_load_dwordx2 %0, %1, off sc0\n\ts_waitcnt vmcnt(0)"
                 : "=v"(u) : "v"(p) : "memory");
    return u;
}
__device__ __forceinline__ uint64_t ld_slow(uint64_t* p) {
    return __hip_atomic_load(p, __ATOMIC_RELAXED, __HIP_MEMORY_SCOPE_AGENT);
}
__device__ __forceinline__ void publish2(uint64_t* fp, uint64_t* sp,
                                         float v, uint32_t tag) {
    uint64_t u = ((uint64_t)tag << 32) | (uint64_t)__float_as_uint(v);
    __hip_atomic_store(fp, u, __ATOMIC_RELAXED, __HIP_MEMORY_SCOPE_WORKGROUP);
    __hip_atomic_store(sp, u, __ATOMIC_RELAXED, __HIP_MEMORY_SCOPE_AGENT);
}
__device__ __forceinline__ void publish_slow(uint64_t* sp, float v,
                                             uint32_t tag) {
    uint64_t u = ((uint64_t)tag << 32) | (uint64_t)__float_as_uint(v);
    __hip_atomic_store(sp, u, __ATOMIC_RELAXED, __HIP_MEMORY_SCOPE_AGENT);
}
// alternate fast/slow probes; slow probe guarantees progress (R6 form)
__device__ __forceinline__ float poll_both(uint64_t* fp, uint64_t* sp,
                                           uint32_t tag) {
    while (true) {
        uint64_t u = ld_fast(fp);
        if (tag_ok(u, tag)) return tv_val(u);
        u = ld_slow(sp);
        if (tag_ok(u, tag)) return tv_val(u);
    }
}
__device__ __forceinline__ float poll_slow(uint64_t* p, uint32_t tag) {
    while (true) {
        uint64_t u = ld_slow(p);
        if (tag_ok(u, tag)) return tv_val(u);
    }
}

// cross-stage consumer progress (flow control for ring reuse).
// Margin check: producer step sp < consumer_step - 16 + (RING-4) ->
// clobbered slot tag sp-64 is always older than anything still needed.
__device__ __forceinline__ void report(uint64_t* p, int s) {
    uint64_t u = (ACK_MAGIC << 48) | (uint32_t)s;
    __hip_atomic_store(p, u, __ATOMIC_RELAXED, __HIP_MEMORY_SCOPE_AGENT);
}
__device__ __forceinline__ void throttle(uint64_t* prog, int s, int& cached) {
    if (s - cached < RING - 4) return;
    while (true) {
        int mn = 0x7fffffff;
#pragma unroll
        for (int i = 0; i < NB; ++i) {
            uint64_t u = __hip_atomic_load(&prog[i], __ATOMIC_RELAXED,
                                           __HIP_MEMORY_SCOPE_AGENT);
            int v = ((u >> 48) == ACK_MAGIC) ? (int)(uint32_t)u : 0;
            mn = (v < mn) ? v : mn;
        }
        cached = mn;
        if (s - cached < RING - 4) return;
    }
}

__device__ __forceinline__ float fast_tanh(float x) {
    return 1.0f - 2.0f / (__expf(2.0f * x) + 1.0f);
}

__device__ __forceinline__ float mat_part(const float* sh, const float* wreg,
                                          int w) {
    const float4* v4 = (const float4*)&sh[w << 6];
    float a0 = 0.f, a1 = 0.f, a2 = 0.f, a3 = 0.f;
#pragma unroll
    for (int t = 0; t < 16; ++t) {
        float4 x = v4[t];
        a0 += x.x * wreg[4 * t + 0];
        a1 += x.y * wreg[4 * t + 1];
        a2 += x.z * wreg[4 * t + 2];
        a3 += x.w * wreg[4 * t + 3];
    }
    return (a0 + a1) + (a2 + a3);
}

// ---------------------------------------------------------------------------
// X1 = gather(emb, nums) @ Wxh1 + b1
// ---------------------------------------------------------------------------
template <int TM>
__global__ void gemm_rows(const int* __restrict__ nums,
                          const float* __restrict__ emb,
                          const float* __restrict__ W,
                          const float* __restrict__ bias,
                          float* __restrict__ out)
{
    __shared__ float xs[TM][D];
    const int tid = threadIdx.x;               // 256
    const int r0 = blockIdx.x * TM;

    for (int m = 0; m < TM; ++m) {
        const float* xr = emb + (size_t)nums[r0 + m] * D;
        for (int idx = tid; idx < D; idx += 256) xs[m][idx] = xr[idx];
    }
    __syncthreads();

    const int j0 = tid, j1 = tid + 256;
    float acc0[TM], acc1[TM];
#pragma unroll
    for (int m = 0; m < TM; ++m) { acc0[m] = 0.f; acc1[m] = 0.f; }

    for (int k = 0; k < D; ++k) {
        const float w0 = W[(size_t)k * D + j0];
        const float w1 = W[(size_t)k * D + j1];
#pragma unroll
        for (int m = 0; m < TM; ++m) {
            const float x = xs[m][k];
            acc0[m] += x * w0;
            acc1[m] += x * w1;
        }
    }
    const float bb0 = bias[j0], bb1 = bias[j1];
#pragma unroll
    for (int m = 0; m < TM; ++m) {
        out[(size_t)(r0 + m) * D + j0] = acc0[m] + bb0;
        out[(size_t)(r0 + m) * D + j1] = acc1[m] + bb1;
    }
}

__global__ void prep_exp(const float* __restrict__ T, float* __restrict__ expT)
{
    const int i = blockIdx.x * 512 + threadIdx.x;
    expT[i] = __expf(T[i]);
}

// ---------------------------------------------------------------------------
// 5-stage pipeline. Launch 64 blocks; active: stage = blockIdx&7 in [0,5),
// slice = blockIdx>>3 (round-robin puts a stage's 8 blocks on one XCD ->
// fast ring works for self-recurrence; slow ring is always correct).
//  stage 0: h1[s]  = tanh(X1[s]      + Whh1·h1[s-1])   (RNN, ring1 f+s)
//  stage 1: u[s]   = Wxh2·h1[s] + b2                    (FF,  ringU slow)
//  stage 2: h2[s]  = tanh(u[s]       + Whh2·h2[s-1])   (RNN, ring2 f+s)
//  stage 3: O[s]   = Wl·h2[s] + bl                      (FF,  ringO slow)
//  stage 4: CRF forward recursion                        (ringF f+s)
// Publisher = the one wave owning this block's columns (R8).
// RNN/FF stages: ONE barrier per step, part[] double-buffered (R9).
// Cross-stage inputs: slow ring + one-step prefetch (hits in steady state).
// ---------------------------------------------------------------------------
__global__ void __launch_bounds__(512, 1)
pipe_all(const float* __restrict__ X1,
         const float* __restrict__ Whh1,
         const float* __restrict__ Wxh2,
         const float* __restrict__ Whh2,
         const float* __restrict__ b2,
         const float* __restrict__ Wl,
         const float* __restrict__ bl,
         const float* __restrict__ expT,
         uint64_t* __restrict__ ring1f, uint64_t* __restrict__ ring1s,
         uint64_t* __restrict__ ringU,
         uint64_t* __restrict__ ring2f, uint64_t* __restrict__ ring2s,
         uint64_t* __restrict__ ringOs,
         uint64_t* __restrict__ ringFf, uint64_t* __restrict__ ringFs,
         uint64_t* __restrict__ prog1,
         uint64_t* __restrict__ progU,
         uint64_t* __restrict__ prog2,
         uint64_t* __restrict__ progO,
         float* __restrict__ out)
{
    __shared__ float sh1[D];
    __shared__ float part[2][D];
    __shared__ float own[CPB];
    __shared__ float wM[1];

    const int stage = blockIdx.x & 7;
    if (stage >= 5) return;
    const int slice = blockIdx.x >> 3;

    const int tid = threadIdx.x;      // 512
    const int w = tid >> 6, l = tid & 63;
    const int jbase = slice * CPB;
    const bool mine = (w == slice);   // publisher wave (wave-uniform)
    int cached = 0;

    if (stage == 0) {
        // RNN1: h1[s] = tanh(X1[s] + Whh1·h1[s-1])
        float wreg[64];
#pragma unroll
        for (int t = 0; t < 64; ++t)
            wreg[t] = Whh1[(size_t)(w * 64 + t) * D + jbase + l];
        float myreg = 0.f;

        for (int s = 0; s < NSEQ; ++s) {
            const float xpre = mine ? X1[(size_t)s * D + tid] : 0.f;
            float hv;
            if (s == 0)    hv = 0.f;
            else if (mine) hv = myreg;
            else           hv = poll_both(
                               &ring1f[(size_t)((s - 1) & RMASK) * D + tid],
                               &ring1s[(size_t)((s - 1) & RMASK) * D + tid],
                               (uint32_t)(s - 1));
            sh1[tid] = hv;                      // wave-local range
            part[s & 1][tid] = mat_part(sh1, wreg, w);
            __syncthreads();                    // B2: part[s&1] ready
            if (mine) {
                const int c = tid & 63;
                float sum = 0.f;
#pragma unroll
                for (int ww = 0; ww < 8; ++ww) sum += part[s & 1][(ww << 6) + c];
                const float g = fast_tanh(sum + xpre);
                myreg = g;
                throttle(prog1, s, cached);
                publish2(&ring1f[(size_t)(s & RMASK) * D + tid],
                         &ring1s[(size_t)(s & RMASK) * D + tid],
                         g, (uint32_t)s);
            }
        }
    } else if (stage == 1) {
        // FF: u[s] = Wxh2·h1[s] + b2 — no recurrence, latency off-path
        float wreg[64];
#pragma unroll
        for (int t = 0; t < 64; ++t)
            wreg[t] = Wxh2[(size_t)(w * 64 + t) * D + jbase + l];
        const float bpre = mine ? b2[tid] : 0.f;
        uint64_t pre = 0;

        for (int s = 0; s < NSEQ; ++s) {
            float h1v;
            if (tag_ok(pre, (uint32_t)s)) h1v = tv_val(pre);
            else h1v = poll_slow(&ring1s[(size_t)(s & RMASK) * D + tid],
                                 (uint32_t)s);
            sh1[tid] = h1v;
            if (s + 1 < NSEQ)
                pre = ld_slow(&ring1s[(size_t)((s + 1) & RMASK) * D + tid]);
            part[s & 1][tid] = mat_part(sh1, wreg, w);
            __syncthreads();                    // B2
            if (mine) {
                const int c = tid & 63;
                float sum = 0.f;
#pragma unroll
                for (int ww = 0; ww < 8; ++ww) sum += part[s & 1][(ww << 6) + c];
                throttle(progU, s, cached);
                publish_slow(&ringU[(size_t)(s & RMASK) * D + tid],
                             sum + bpre, (uint32_t)s);
            }
            if (tid == 0 && (s & 15) == 15) report(&prog1[slice], s);
        }
    } else if (stage == 2) {
        // RNN2: h2[s] = tanh(u[s] + Whh2·h2[s-1]) — same shape as stage 0
        float wreg[64];
#pragma unroll
        for (int t = 0; t < 64; ++t)
            wreg[t] = Whh2[(size_t)(w * 64 + t) * D + jbase + l];
        float myreg = 0.f;
        uint64_t preU = 0;

        for (int s = 0; s < NSEQ; ++s) {
            float upre = 0.f;
            if (mine) {
                if (tag_ok(preU, (uint32_t)s)) upre = tv_val(preU);
                else upre = poll_slow(&ringU[(size_t)(s & RMASK) * D + tid],
                                      (uint32_t)s);
            }
            float hv;
            if (s == 0)    hv = 0.f;
            else if (mine) hv = myreg;
            else           hv = poll_both(
                               &ring2f[(size_t)((s - 1) & RMASK) * D + tid],
                               &ring2s[(size_t)((s - 1) & RMASK) * D + tid],
                               (uint32_t)(s - 1));
            sh1[tid] = hv;
            if (mine && s + 1 < NSEQ)
                preU = ld_slow(&ringU[(size_t)((s + 1) & RMASK) * D + tid]);
            part[s & 1][tid] = mat_part(sh1, wreg, w);
            __syncthreads();                    // B2
            if (mine) {
                const int c = tid & 63;
                float sum = 0.f;
#pragma unroll
                for (int ww = 0; ww < 8; ++ww) sum += part[s & 1][(ww << 6) + c];
                const float g = fast_tanh(sum + upre);
                myreg = g;
                throttle(prog2, s, cached);
                publish2(&ring2f[(size_t)(s & RMASK) * D + tid],
                         &ring2s[(size_t)(s & RMASK) * D + tid],
                         g, (uint32_t)s);
            }
            if (tid == 0 && (s & 15) == 15) report(&progU[slice], s);
        }
    } else if (stage == 3) {
        // FF: O[s] = Wl·h2[s] + bl
        float wreg[64];
#pragma unroll
        for (int t = 0; t < 64; ++t)
            wreg[t] = Wl[(size_t)(w * 64 + t) * V + jbase + l];
        const float bpre = mine ? bl[tid] : 0.f;
        uint64_t pre = 0;

        for (int s = 0; s < NSEQ; ++s) {
            float hv;
            if (tag_ok(pre, (uint32_t)s)) hv = tv_val(pre);
            else hv = poll_slow(&ring2s[(size_t)(s & RMASK) * D + tid],
                                (uint32_t)s);
            sh1[tid] = hv;
            if (s + 1 < NSEQ)
                pre = ld_slow(&ring2s[(size_t)((s + 1) & RMASK) * D + tid]);
            part[s & 1][tid] = mat_part(sh1, wreg, w);
            __syncthreads();                    // B2
            if (mine) {
                const int c = tid & 63;
                float sum = 0.f;
#pragma unroll
                for (int ww = 0; ww < 8; ++ww) sum += part[s & 1][(ww << 6) + c];
                throttle(progO, s, cached);
                publish_slow(&ringOs[(size_t)(s & RMASK) * V + tid],
                             sum + bpre, (uint32_t)s);
            }
            if (tid == 0 && (s & 15) == 15) report(&prog2[slice], s);
        }
    } else {
        // forward CRF (R6/R9-measured structure, unchanged):
        // f_s[k] = O[s][k] + LSE_j(f_{s-1}[j] + T[j,k]); out = f_{n-1}[EOS=1]
        // Shift M = f_{s-1}[jbase] via wM[0]; exact LSE shift, absmax=0.0.
        const int lcol = (w << 3) + (l & 7);
        const int gcol = jbase + lcol;
        const bool pub = (l < 8);
        const bool ownr = (tid >= jbase) && (tid < jbase + CPB);
        float wreg[64];
#pragma unroll
        for (int t = 0; t < 64; ++t)
            wreg[t] = expT[(size_t)(w * 64 + t) * V + jbase + l];

        float creg;
        if (tid == 0) { creg = poll_slow(&ringOs[0], 0u); wM[0] = creg; }
        else creg = -1e30f;
        __syncthreads();   // one-time: initial M visible
        uint64_t preO = 0;

        for (int s = 1; s < NSEQ; ++s) {
            const float M = wM[0];   // written last iter, ordered by B3
            if (s > 1) {
                if (ownr) creg = own[tid - jbase];
                else      creg = poll_both(
                              &ringFf[(size_t)((s - 1) & RMASK) * V + tid],
                              &ringFs[(size_t)((s - 1) & RMASK) * V + tid],
                              (uint32_t)(s - 1));
            }
            float opre = 0.f;
            if (pub) {
                if (tag_ok(preO, (uint32_t)s)) opre = tv_val(preO);
                else opre = poll_slow(&ringOs[(size_t)(s & RMASK) * V + gcol],
                                      (uint32_t)s);
            }

            sh1[tid] = __expf(creg - M);
            __syncthreads();                       // B1
            if (pub && s + 1 < NSEQ)
                preO = ld_slow(&ringOs[(size_t)((s + 1) & RMASK) * V + gcol]);
            part[0][tid] = mat_part(sh1, wreg, w);
            __syncthreads();                       // B2

            if (pub) {
                float sum = 0.f;
#pragma unroll
                for (int ww = 0; ww < 8; ++ww) sum += part[0][(ww << 6) + lcol];
                const float cn = opre + M + __logf(sum);
                if (s < NSEQ - 1) {
                    own[lcol] = cn;
                    if (lcol == 0) wM[0] = cn;     // next step's shift
                    publish2(&ringFf[(size_t)(s & RMASK) * V + gcol],
                             &ringFs[(size_t)(s & RMASK) * V + gcol],
                             cn, (uint32_t)s);
                } else if (gcol == 1) {
                    out[0] = cn;           // f_{n-1}[EOS=1]
                }
            }
            if (tid == 0 && (s & 15) == 15) report(&progO[slice], s);
            __syncthreads();   // B3: protects own[]/wM for next iteration
        }
    }
}

// ---------------------------------------------------------------------------
extern "C" void kernel_launch(void* const* d_in, const int* in_sizes, int n_in,
                              void* d_out, int out_size, void* d_ws, size_t ws_size,
                              hipStream_t stream)
{
    const int*   nums = (const int*)d_in[0];
    const float* emb  = (const float*)d_in[1];
    const float* Wxh1 = (const float*)d_in[2];
    const float* Whh1 = (const float*)d_in[3];
    const float* b1   = (const float*)d_in[4];
    const float* Wxh2 = (const float*)d_in[5];
    const float* Whh2 = (const float*)d_in[6];
    const float* b2   = (const float*)d_in[7];
    const float* Wl   = (const float*)d_in[8];
    const float* bl   = (const float*)d_in[9];
    const float* T    = (const float*)d_in[10];
    float* out = (float*)d_out;

    // workspace (~7.5 MB): X1 + expT + 8 rings (256KB each) + progress
    float* Xbuf = (float*)d_ws;                         // [NSEQ*D]
    float* expT = Xbuf + (size_t)NSEQ * D;              // [V*V]
    uint64_t* ring1f = (uint64_t*)(expT + (size_t)V * V);
    uint64_t* ring1s = ring1f + (size_t)RING * D;
    uint64_t* ringU  = ring1s + (size_t)RING * D;
    uint64_t* ring2f = ringU  + (size_t)RING * D;
    uint64_t* ring2s = ring2f + (size_t)RING * D;
    uint64_t* ringOs = ring2s + (size_t)RING * D;
    uint64_t* ringFf = ringOs + (size_t)RING * V;
    uint64_t* ringFs = ringFf + (size_t)RING * V;
    uint64_t* prog1  = ringFs + (size_t)RING * V;       // [NB]
    uint64_t* progU  = prog1 + NB;                      // [NB]
    uint64_t* prog2  = progU + NB;                      // [NB]
    uint64_t* progO  = prog2 + NB;                      // [NB]

    gemm_rows<8><<<NSEQ / 8, 256, 0, stream>>>(nums, emb, Wxh1, b1, Xbuf);
    prep_exp<<<V * V / 512, 512, 0, stream>>>(T, expT);
    pipe_all<<<64, 512, 0, stream>>>(Xbuf, Whh1, Wxh2, Whh2, b2, Wl, bl, expT,
                                     ring1f, ring1s, ringU, ring2f, ring2s,
                                     ringOs, ringFf, ringFs,
                                     prog1, progU, prog2, progO, out);
}

// Round 13
// 2843.126 us; speedup vs baseline: 1.7868x; 1.0193x over previous
//
#include <hip/hip_runtime.h>
#include <math.h>
#include <stdint.h>

#define NSEQ 2048
#define D 512
#define V 512
#define NB 8            // column-slice blocks per pipeline stage
#define CPB 64          // D / NB
#define RING 64         // ring depth (steps)
#define RMASK (RING - 1)
#define ACK_MAGIC 0x0ACEull

// ---------------------------------------------------------------------------
// Dual-path tagged sync, NO sticky state. poll_both is the R6-measured-good
// SERIAL form. Detect-mechanics history (do not revisit):
//   R7  always-wait-slow "overlap":       3715 -> 4335us
//   R10 flag-gated wave detect:           3493 -> 5515us
// Structural removals won: R8 pub-wave remap, R9 B1 removal, R11 stage split
// (3493 -> 2765us). R12: apply the R8+R9 patterns to the CRF stage + a
// two-step-delayed uniform LSE shift (wM[2]) so its ordering needs no extra
// barrier -> CRF runs ONE barrier/step like the RNN/FF stages.
//  fast ring: plain (workgroup-scope) store -> producer XCD's L2; sc0 load
//             hits the shared L2 iff consumer is on the SAME XCD (~250cy).
//  slow ring: relaxed agent-scope atomics -> IF-level, any placement (~700cy).
// ---------------------------------------------------------------------------
__device__ __forceinline__ bool tag_ok(uint64_t u, uint32_t tag) {
    return (uint32_t)(u >> 32) == tag;
}
__device__ __forceinline__ float tv_val(uint64_t u) {
    return __uint_as_float((uint32_t)u);
}
__device__ __forceinline__ uint64_t ld_fast(const uint64_t* p) {
    uint64_t u;
    asm volatile("global_load_dwordx2 %0, %1, off sc0\n\ts_waitcnt vmcnt(0)"
                 : "=v"(u) : "v"(p) : "memory");
    return u;
}
__device__ __forceinline__ uint64_t ld_slow(uint64_t* p) {
    return __hip_atomic_load(p, __ATOMIC_RELAXED, __HIP_MEMORY_SCOPE_AGENT);
}
__device__ __forceinline__ void publish2(uint64_t* fp, uint64_t* sp,
                                         float v, uint32_t tag) {
    uint64_t u = ((uint64_t)tag << 32) | (uint64_t)__float_as_uint(v);
    __hip_atomic_store(fp, u, __ATOMIC_RELAXED, __HIP_MEMORY_SCOPE_WORKGROUP);
    __hip_atomic_store(sp, u, __ATOMIC_RELAXED, __HIP_MEMORY_SCOPE_AGENT);
}
__device__ __forceinline__ void publish_slow(uint64_t* sp, float v,
                                             uint32_t tag) {
    uint64_t u = ((uint64_t)tag << 32) | (uint64_t)__float_as_uint(v);
    __hip_atomic_store(sp, u, __ATOMIC_RELAXED, __HIP_MEMORY_SCOPE_AGENT);
}
// alternate fast/slow probes; slow probe guarantees progress (R6 form)
__device__ __forceinline__ float poll_both(uint64_t* fp, uint64_t* sp,
                                           uint32_t tag) {
    while (true) {
        uint64_t u = ld_fast(fp);
        if (tag_ok(u, tag)) return tv_val(u);
        u = ld_slow(sp);
        if (tag_ok(u, tag)) return tv_val(u);
    }
}
__device__ __forceinline__ float poll_slow(uint64_t* p, uint32_t tag) {
    while (true) {
        uint64_t u = ld_slow(p);
        if (tag_ok(u, tag)) return tv_val(u);
    }
}

// cross-stage consumer progress (flow control for ring reuse).
// Margin check: producer step sp < consumer_step - 16 + (RING-4) ->
// clobbered slot tag sp-64 is always older than anything still needed.
__device__ __forceinline__ void report(uint64_t* p, int s) {
    uint64_t u = (ACK_MAGIC << 48) | (uint32_t)s;
    __hip_atomic_store(p, u, __ATOMIC_RELAXED, __HIP_MEMORY_SCOPE_AGENT);
}
__device__ __forceinline__ void throttle(uint64_t* prog, int s, int& cached) {
    if (s - cached < RING - 4) return;
    while (true) {
        int mn = 0x7fffffff;
#pragma unroll
        for (int i = 0; i < NB; ++i) {
            uint64_t u = __hip_atomic_load(&prog[i], __ATOMIC_RELAXED,
                                           __HIP_MEMORY_SCOPE_AGENT);
            int v = ((u >> 48) == ACK_MAGIC) ? (int)(uint32_t)u : 0;
            mn = (v < mn) ? v : mn;
        }
        cached = mn;
        if (s - cached < RING - 4) return;
    }
}

__device__ __forceinline__ float fast_tanh(float x) {
    return 1.0f - 2.0f / (__expf(2.0f * x) + 1.0f);
}

__device__ __forceinline__ float mat_part(const float* sh, const float* wreg,
                                          int w) {
    const float4* v4 = (const float4*)&sh[w << 6];
    float a0 = 0.f, a1 = 0.f, a2 = 0.f, a3 = 0.f;
#pragma unroll
    for (int t = 0; t < 16; ++t) {
        float4 x = v4[t];
        a0 += x.x * wreg[4 * t + 0];
        a1 += x.y * wreg[4 * t + 1];
        a2 += x.z * wreg[4 * t + 2];
        a3 += x.w * wreg[4 * t + 3];
    }
    return (a0 + a1) + (a2 + a3);
}

// ---------------------------------------------------------------------------
// X1 = gather(emb, nums) @ Wxh1 + b1
// ---------------------------------------------------------------------------
template <int TM>
__global__ void gemm_rows(const int* __restrict__ nums,
                          const float* __restrict__ emb,
                          const float* __restrict__ W,
                          const float* __restrict__ bias,
                          float* __restrict__ out)
{
    __shared__ float xs[TM][D];
    const int tid = threadIdx.x;               // 256
    const int r0 = blockIdx.x * TM;

    for (int m = 0; m < TM; ++m) {
        const float* xr = emb + (size_t)nums[r0 + m] * D;
        for (int idx = tid; idx < D; idx += 256) xs[m][idx] = xr[idx];
    }
    __syncthreads();

    const int j0 = tid, j1 = tid + 256;
    float acc0[TM], acc1[TM];
#pragma unroll
    for (int m = 0; m < TM; ++m) { acc0[m] = 0.f; acc1[m] = 0.f; }

    for (int k = 0; k < D; ++k) {
        const float w0 = W[(size_t)k * D + j0];
        const float w1 = W[(size_t)k * D + j1];
#pragma unroll
        for (int m = 0; m < TM; ++m) {
            const float x = xs[m][k];
            acc0[m] += x * w0;
            acc1[m] += x * w1;
        }
    }
    const float bb0 = bias[j0], bb1 = bias[j1];
#pragma unroll
    for (int m = 0; m < TM; ++m) {
        out[(size_t)(r0 + m) * D + j0] = acc0[m] + bb0;
        out[(size_t)(r0 + m) * D + j1] = acc1[m] + bb1;
    }
}

__global__ void prep_exp(const float* __restrict__ T, float* __restrict__ expT)
{
    const int i = blockIdx.x * 512 + threadIdx.x;
    expT[i] = __expf(T[i]);
}

// ---------------------------------------------------------------------------
// 5-stage pipeline. Launch 64 blocks; active: stage = blockIdx&7 in [0,5),
// slice = blockIdx>>3 (round-robin puts a stage's 8 blocks on one XCD ->
// fast ring works for self-recurrence; slow ring is always correct).
//  stage 0: h1[s]  = tanh(X1[s]      + Whh1·h1[s-1])   (RNN, ring1 f+s)
//  stage 1: u[s]   = Wxh2·h1[s] + b2                    (FF,  ringU slow)
//  stage 2: h2[s]  = tanh(u[s]       + Whh2·h2[s-1])   (RNN, ring2 f+s)
//  stage 3: O[s]   = Wl·h2[s] + bl                      (FF,  ringO slow)
//  stage 4: CRF forward recursion                        (ringF f+s)
// All stages: publisher = wave `slice` (R8), ONE barrier/step with part[]
// double-buffer (R9). R12: CRF brought to this form; uniform LSE shift is
// two-step-delayed M = f_{s-2}[jbase] via wM[2] (write after B2(s), read at
// s+2 ordered by B2(s+1)); exact for any block-uniform M, drift ~7/step so
// exp args stay far below fp32 overflow.
// ---------------------------------------------------------------------------
__global__ void __launch_bounds__(512, 1)
pipe_all(const float* __restrict__ X1,
         const float* __restrict__ Whh1,
         const float* __restrict__ Wxh2,
         const float* __restrict__ Whh2,
         const float* __restrict__ b2,
         const float* __restrict__ Wl,
         const float* __restrict__ bl,
         const float* __restrict__ expT,
         uint64_t* __restrict__ ring1f, uint64_t* __restrict__ ring1s,
         uint64_t* __restrict__ ringU,
         uint64_t* __restrict__ ring2f, uint64_t* __restrict__ ring2s,
         uint64_t* __restrict__ ringOs,
         uint64_t* __restrict__ ringFf, uint64_t* __restrict__ ringFs,
         uint64_t* __restrict__ prog1,
         uint64_t* __restrict__ progU,
         uint64_t* __restrict__ prog2,
         uint64_t* __restrict__ progO,
         float* __restrict__ out)
{
    __shared__ float sh1[D];
    __shared__ float part[2][D];
    __shared__ float wM[2];

    const int stage = blockIdx.x & 7;
    if (stage >= 5) return;
    const int slice = blockIdx.x >> 3;

    const int tid = threadIdx.x;      // 512
    const int w = tid >> 6, l = tid & 63;
    const int jbase = slice * CPB;
    const bool mine = (w == slice);   // publisher wave (wave-uniform)
    int cached = 0;

    if (stage == 0) {
        // RNN1: h1[s] = tanh(X1[s] + Whh1·h1[s-1])
        float wreg[64];
#pragma unroll
        for (int t = 0; t < 64; ++t)
            wreg[t] = Whh1[(size_t)(w * 64 + t) * D + jbase + l];
        float myreg = 0.f;

        for (int s = 0; s < NSEQ; ++s) {
            const float xpre = mine ? X1[(size_t)s * D + tid] : 0.f;
            float hv;
            if (s == 0)    hv = 0.f;
            else if (mine) hv = myreg;
            else           hv = poll_both(
                               &ring1f[(size_t)((s - 1) & RMASK) * D + tid],
                               &ring1s[(size_t)((s - 1) & RMASK) * D + tid],
                               (uint32_t)(s - 1));
            sh1[tid] = hv;                      // wave-local range
            part[s & 1][tid] = mat_part(sh1, wreg, w);
            __syncthreads();                    // B2: part[s&1] ready
            if (mine) {
                const int c = tid & 63;
                float sum = 0.f;
#pragma unroll
                for (int ww = 0; ww < 8; ++ww) sum += part[s & 1][(ww << 6) + c];
                const float g = fast_tanh(sum + xpre);
                myreg = g;
                throttle(prog1, s, cached);
                publish2(&ring1f[(size_t)(s & RMASK) * D + tid],
                         &ring1s[(size_t)(s & RMASK) * D + tid],
                         g, (uint32_t)s);
            }
        }
    } else if (stage == 1) {
        // FF: u[s] = Wxh2·h1[s] + b2 — no recurrence, latency off-path
        float wreg[64];
#pragma unroll
        for (int t = 0; t < 64; ++t)
            wreg[t] = Wxh2[(size_t)(w * 64 + t) * D + jbase + l];
        const float bpre = mine ? b2[tid] : 0.f;
        uint64_t pre = 0;

        for (int s = 0; s < NSEQ; ++s) {
            float h1v;
            if (tag_ok(pre, (uint32_t)s)) h1v = tv_val(pre);
            else h1v = poll_slow(&ring1s[(size_t)(s & RMASK) * D + tid],
                                 (uint32_t)s);
            sh1[tid] = h1v;
            if (s + 1 < NSEQ)
                pre = ld_slow(&ring1s[(size_t)((s + 1) & RMASK) * D + tid]);
            part[s & 1][tid] = mat_part(sh1, wreg, w);
            __syncthreads();                    // B2
            if (mine) {
                const int c = tid & 63;
                float sum = 0.f;
#pragma unroll
                for (int ww = 0; ww < 8; ++ww) sum += part[s & 1][(ww << 6) + c];
                throttle(progU, s, cached);
                publish_slow(&ringU[(size_t)(s & RMASK) * D + tid],
                             sum + bpre, (uint32_t)s);
            }
            if (tid == 0 && (s & 15) == 15) report(&prog1[slice], s);
        }
    } else if (stage == 2) {
        // RNN2: h2[s] = tanh(u[s] + Whh2·h2[s-1]) — same shape as stage 0
        float wreg[64];
#pragma unroll
        for (int t = 0; t < 64; ++t)
            wreg[t] = Whh2[(size_t)(w * 64 + t) * D + jbase + l];
        float myreg = 0.f;
        uint64_t preU = 0;

        for (int s = 0; s < NSEQ; ++s) {
            float upre = 0.f;
            if (mine) {
                if (tag_ok(preU, (uint32_t)s)) upre = tv_val(preU);
                else upre = poll_slow(&ringU[(size_t)(s & RMASK) * D + tid],
                                      (uint32_t)s);
            }
            float hv;
            if (s == 0)    hv = 0.f;
            else if (mine) hv = myreg;
            else           hv = poll_both(
                               &ring2f[(size_t)((s - 1) & RMASK) * D + tid],
                               &ring2s[(size_t)((s - 1) & RMASK) * D + tid],
                               (uint32_t)(s - 1));
            sh1[tid] = hv;
            if (mine && s + 1 < NSEQ)
                preU = ld_slow(&ringU[(size_t)((s + 1) & RMASK) * D + tid]);
            part[s & 1][tid] = mat_part(sh1, wreg, w);
            __syncthreads();                    // B2
            if (mine) {
                const int c = tid & 63;
                float sum = 0.f;
#pragma unroll
                for (int ww = 0; ww < 8; ++ww) sum += part[s & 1][(ww << 6) + c];
                const float g = fast_tanh(sum + upre);
                myreg = g;
                throttle(prog2, s, cached);
                publish2(&ring2f[(size_t)(s & RMASK) * D + tid],
                         &ring2s[(size_t)(s & RMASK) * D + tid],
                         g, (uint32_t)s);
            }
            if (tid == 0 && (s & 15) == 15) report(&progU[slice], s);
        }
    } else if (stage == 3) {
        // FF: O[s] = Wl·h2[s] + bl
        float wreg[64];
#pragma unroll
        for (int t = 0; t < 64; ++t)
            wreg[t] = Wl[(size_t)(w * 64 + t) * V + jbase + l];
        const float bpre = mine ? bl[tid] : 0.f;
        uint64_t pre = 0;

        for (int s = 0; s < NSEQ; ++s) {
            float hv;
            if (tag_ok(pre, (uint32_t)s)) hv = tv_val(pre);
            else hv = poll_slow(&ring2s[(size_t)(s & RMASK) * D + tid],
                                (uint32_t)s);
            sh1[tid] = hv;
            if (s + 1 < NSEQ)
                pre = ld_slow(&ring2s[(size_t)((s + 1) & RMASK) * D + tid]);
            part[s & 1][tid] = mat_part(sh1, wreg, w);
            __syncthreads();                    // B2
            if (mine) {
                const int c = tid & 63;
                float sum = 0.f;
#pragma unroll
                for (int ww = 0; ww < 8; ++ww) sum += part[s & 1][(ww << 6) + c];
                throttle(progO, s, cached);
                publish_slow(&ringOs[(size_t)(s & RMASK) * V + tid],
                             sum + bpre, (uint32_t)s);
            }
            if (tid == 0 && (s & 15) == 15) report(&prog2[slice], s);
        }
    } else {
        // CRF forward (R12 modernized): f_s[k] = O[s][k] + M +
        //   log(sum_j expT[j][k]·exp(f_{s-1}[j] − M));  out = f_{n-1}[EOS=1]
        // Publisher wave keeps f in register (myf); others poll ringF.
        // sh1 is wave-local (wave w writes/reads [w*64..]) -> no B1; part[]
        // double-buffered -> single B2/step. M = f_{s-2}[jbase] via wM[2]:
        // write wM[s&1] after B2(s), read at s+2 (ordered by B2(s+1)).
        // Exact LSE shift for any uniform M; |f_s − f_{s-2}| ~ 14 so exp
        // args stay ~e^35 max, far below fp32 overflow.
        float wreg[64];
#pragma unroll
        for (int t = 0; t < 64; ++t)
            wreg[t] = expT[(size_t)(w * 64 + t) * V + jbase + l];

        float f0 = -1e30f;
        if (tid == 0) {
            f0 = poll_slow(&ringOs[0], 0u);   // O[0][BOS=0]
            wM[0] = f0; wM[1] = f0;
        }
        __syncthreads();   // one-time: wM init visible
        float myf = f0;    // f_{s-1}[tid] for publisher lanes (init = f_0)
        uint64_t preO = 0;

        for (int s = 1; s < NSEQ; ++s) {
            const float M = wM[s & 1];   // f_{s-2}[jbase] (init f_0[BOS])
            float opre = 0.f;
            if (mine) {
                if (tag_ok(preO, (uint32_t)s)) opre = tv_val(preO);
                else opre = poll_slow(&ringOs[(size_t)(s & RMASK) * V + tid],
                                      (uint32_t)s);
            }
            float cv;
            if (s == 1)    cv = myf;   // f_0[tid]: tid0=O[0][0], else -1e30
            else if (mine) cv = myf;
            else           cv = poll_both(
                               &ringFf[(size_t)((s - 1) & RMASK) * V + tid],
                               &ringFs[(size_t)((s - 1) & RMASK) * V + tid],
                               (uint32_t)(s - 1));
            sh1[tid] = __expf(cv - M);          // wave-local range
            if (mine && s + 1 < NSEQ)
                preO = ld_slow(&ringOs[(size_t)((s + 1) & RMASK) * V + tid]);
            part[s & 1][tid] = mat_part(sh1, wreg, w);
            __syncthreads();                    // B2
            if (mine) {
                const int c = tid & 63;
                float sum = 0.f;
#pragma unroll
                for (int ww = 0; ww < 8; ++ww) sum += part[s & 1][(ww << 6) + c];
                const float cn = opre + M + __logf(sum);
                myf = cn;
                if (s < NSEQ - 1) {
                    if (tid == jbase) wM[s & 1] = cn;   // M for step s+2
                    publish2(&ringFf[(size_t)(s & RMASK) * V + tid],
                             &ringFs[(size_t)(s & RMASK) * V + tid],
                             cn, (uint32_t)s);
                } else if (tid == 1) {
                    out[0] = cn;       // EOS col; slice 0's publisher only
                }
            }
            if (tid == 0 && (s & 15) == 15) report(&progO[slice], s);
        }
    }
}

// ---------------------------------------------------------------------------
extern "C" void kernel_launch(void* const* d_in, const int* in_sizes, int n_in,
                              void* d_out, int out_size, void* d_ws, size_t ws_size,
                              hipStream_t stream)
{
    const int*   nums = (const int*)d_in[0];
    const float* emb  = (const float*)d_in[1];
    const float* Wxh1 = (const float*)d_in[2];
    const float* Whh1 = (const float*)d_in[3];
    const float* b1   = (const float*)d_in[4];
    const float* Wxh2 = (const float*)d_in[5];
    const float* Whh2 = (const float*)d_in[6];
    const float* b2   = (const float*)d_in[7];
    const float* Wl   = (const float*)d_in[8];
    const float* bl   = (const float*)d_in[9];
    const float* T    = (const float*)d_in[10];
    float* out = (float*)d_out;

    // workspace (~7.5 MB): X1 + expT + 8 rings (256KB each) + progress
    float* Xbuf = (float*)d_ws;                         // [NSEQ*D]
    float* expT = Xbuf + (size_t)NSEQ * D;              // [V*V]
    uint64_t* ring1f = (uint64_t*)(expT + (size_t)V * V);
    uint64_t* ring1s = ring1f + (size_t)RING * D;
    uint64_t* ringU  = ring1s + (size_t)RING * D;
    uint64_t* ring2f = ringU  + (size_t)RING * D;
    uint64_t* ring2s = ring2f + (size_t)RING * D;
    uint64_t* ringOs = ring2s + (size_t)RING * D;
    uint64_t* ringFf = ringOs + (size_t)RING * V;
    uint64_t* ringFs = ringFf + (size_t)RING * V;
    uint64_t* prog1  = ringFs + (size_t)RING * V;       // [NB]
    uint64_t* progU  = prog1 + NB;                      // [NB]
    uint64_t* prog2  = progU + NB;                      // [NB]
    uint64_t* progO  = prog2 + NB;                      // [NB]

    gemm_rows<8><<<NSEQ / 8, 256, 0, stream>>>(nums, emb, Wxh1, b1, Xbuf);
    prep_exp<<<V * V / 512, 512, 0, stream>>>(T, expT);
    pipe_all<<<64, 512, 0, stream>>>(Xbuf, Whh1, Wxh2, Whh2, b2, Wl, bl, expT,
                                     ring1f, ring1s, ringU, ring2f, ring2s,
                                     ringOs, ringFf, ringFs,
                                     prog1, progU, prog2, progO, out);
}